// Round 1
// baseline (621.264 us; speedup 1.0000x reference)
//
#include <hip/hip_runtime.h>
#include <hip/hip_bf16.h>

// Sizes fixed by the reference: B=4, N=1024, DIM=768, H=12, Dh=64.
// ws layout (fp32):
//   qkv : [4096][2304]                37.75 MB
//   S   : [4][12][1024][1024]        201.33 MB   (scores, processed in place)
//   ao  : [4096][768]                 12.58 MB   (attn output, heads merged)
// total ~251.7 MB

#define BDIM 768
#define NSEQ 1024
#define NB 4
#define NH 12

// ---------------------------------------------------------------------------
// Generic 64x64-tile NT GEMM: C[i][j] = alpha * sum_k A[i*lda+k]*B[j*ldb+k] (+bias[j])
// Batch offset: z1 = z/zdiv, z2 = z%zdiv; ptr += z1*s1 + z2*s2.
// Requires M,N multiples of 64, K multiple of 16, all pointers 16B aligned.
// ---------------------------------------------------------------------------
__global__ __launch_bounds__(256) void gemm_nt(
    const float* __restrict__ A, const float* __restrict__ B, float* __restrict__ C,
    int lda, int ldb, int ldc, int K, int zdiv,
    long long sA1, long long sA2, long long sB1, long long sB2,
    long long sC1, long long sC2,
    const float* __restrict__ bias, float alpha)
{
    const int z = blockIdx.z;
    const int z1 = z / zdiv, z2 = z % zdiv;
    A += z1 * sA1 + z2 * sA2;
    B += z1 * sB1 + z2 * sB2;
    C += z1 * sC1 + z2 * sC2;

    const int n0 = blockIdx.x * 64;
    const int m0 = blockIdx.y * 64;
    const int tid = threadIdx.x;
    const int tx = tid & 15, ty = tid >> 4;
    const int lrow = tid >> 2;          // 0..63
    const int lkv = (tid & 3) << 2;     // 0,4,8,12

    __shared__ float As[16][72];        // [k][m], +8 pad keeps rows 16B aligned
    __shared__ float Bs[16][72];        // [k][n]

    float acc[4][4] = {{0.f,0.f,0.f,0.f},{0.f,0.f,0.f,0.f},
                       {0.f,0.f,0.f,0.f},{0.f,0.f,0.f,0.f}};

    const float* Aptr = A + (long long)(m0 + lrow) * lda + lkv;
    const float* Bptr = B + (long long)(n0 + lrow) * ldb + lkv;

    for (int k0 = 0; k0 < K; k0 += 16) {
        float4 av = *(const float4*)(Aptr + k0);
        float4 bv = *(const float4*)(Bptr + k0);
        __syncthreads();
        As[lkv + 0][lrow] = av.x; As[lkv + 1][lrow] = av.y;
        As[lkv + 2][lrow] = av.z; As[lkv + 3][lrow] = av.w;
        Bs[lkv + 0][lrow] = bv.x; Bs[lkv + 1][lrow] = bv.y;
        Bs[lkv + 2][lrow] = bv.z; Bs[lkv + 3][lrow] = bv.w;
        __syncthreads();
#pragma unroll
        for (int kk = 0; kk < 16; ++kk) {
            float4 a4 = *(const float4*)&As[kk][ty << 2];
            float4 b4 = *(const float4*)&Bs[kk][tx << 2];
            float aa[4] = {a4.x, a4.y, a4.z, a4.w};
            float bb[4] = {b4.x, b4.y, b4.z, b4.w};
#pragma unroll
            for (int i = 0; i < 4; ++i)
#pragma unroll
                for (int j = 0; j < 4; ++j)
                    acc[i][j] = fmaf(aa[i], bb[j], acc[i][j]);
        }
    }

    const int col = n0 + (tx << 2);
    float badd[4] = {0.f, 0.f, 0.f, 0.f};
    if (bias) {
        badd[0] = bias[col + 0]; badd[1] = bias[col + 1];
        badd[2] = bias[col + 2]; badd[3] = bias[col + 3];
    }
#pragma unroll
    for (int i = 0; i < 4; ++i) {
        const int row = m0 + (ty << 2) + i;
        float4 o;
        o.x = acc[i][0] * alpha + badd[0];
        o.y = acc[i][1] * alpha + badd[1];
        o.z = acc[i][2] * alpha + badd[2];
        o.w = acc[i][3] * alpha + badd[3];
        *(float4*)(C + (long long)row * ldc + col) = o;
    }
}

// ---------------------------------------------------------------------------
// NN GEMM: C[i][j] = alpha * sum_k A[i*lda+k]*B[k*ldb+j]  (B row-major [K][N])
// Same tiling; only the B staging differs.
// ---------------------------------------------------------------------------
__global__ __launch_bounds__(256) void gemm_nn(
    const float* __restrict__ A, const float* __restrict__ B, float* __restrict__ C,
    int lda, int ldb, int ldc, int K, int zdiv,
    long long sA1, long long sA2, long long sB1, long long sB2,
    long long sC1, long long sC2,
    const float* __restrict__ bias, float alpha)
{
    const int z = blockIdx.z;
    const int z1 = z / zdiv, z2 = z % zdiv;
    A += z1 * sA1 + z2 * sA2;
    B += z1 * sB1 + z2 * sB2;
    C += z1 * sC1 + z2 * sC2;

    const int n0 = blockIdx.x * 64;
    const int m0 = blockIdx.y * 64;
    const int tid = threadIdx.x;
    const int tx = tid & 15, ty = tid >> 4;
    const int lrow = tid >> 2;          // 0..63  (A rows)
    const int lkv = (tid & 3) << 2;     // 0,4,8,12 (A k-vec)
    const int bkrow = tid >> 4;         // 0..15  (B k-row)
    const int bj = (tid & 15) << 2;     // 0..60  (B col-vec)

    __shared__ float As[16][72];        // [k][m]
    __shared__ float Bs[16][72];        // [k][n]

    float acc[4][4] = {{0.f,0.f,0.f,0.f},{0.f,0.f,0.f,0.f},
                       {0.f,0.f,0.f,0.f},{0.f,0.f,0.f,0.f}};

    const float* Aptr = A + (long long)(m0 + lrow) * lda + lkv;

    for (int k0 = 0; k0 < K; k0 += 16) {
        float4 av = *(const float4*)(Aptr + k0);
        float4 bv = *(const float4*)(B + (long long)(k0 + bkrow) * ldb + n0 + bj);
        __syncthreads();
        As[lkv + 0][lrow] = av.x; As[lkv + 1][lrow] = av.y;
        As[lkv + 2][lrow] = av.z; As[lkv + 3][lrow] = av.w;
        *(float4*)&Bs[bkrow][bj] = bv;
        __syncthreads();
#pragma unroll
        for (int kk = 0; kk < 16; ++kk) {
            float4 a4 = *(const float4*)&As[kk][ty << 2];
            float4 b4 = *(const float4*)&Bs[kk][tx << 2];
            float aa[4] = {a4.x, a4.y, a4.z, a4.w};
            float bb[4] = {b4.x, b4.y, b4.z, b4.w};
#pragma unroll
            for (int i = 0; i < 4; ++i)
#pragma unroll
                for (int j = 0; j < 4; ++j)
                    acc[i][j] = fmaf(aa[i], bb[j], acc[i][j]);
        }
    }

    const int col = n0 + (tx << 2);
    float badd[4] = {0.f, 0.f, 0.f, 0.f};
    if (bias) {
        badd[0] = bias[col + 0]; badd[1] = bias[col + 1];
        badd[2] = bias[col + 2]; badd[3] = bias[col + 3];
    }
#pragma unroll
    for (int i = 0; i < 4; ++i) {
        const int row = m0 + (ty << 2) + i;
        float4 o;
        o.x = acc[i][0] * alpha + badd[0];
        o.y = acc[i][1] * alpha + badd[1];
        o.z = acc[i][2] * alpha + badd[2];
        o.w = acc[i][3] * alpha + badd[3];
        *(float4*)(C + (long long)row * ldc + col) = o;
    }
}

// ---------------------------------------------------------------------------
// Fused: pre-mix (W_l,b_l) -> softmax -> post-mix (W_w,b_w) -> attnscale.
// One block per (b,n) row; all 12 heads in LDS (48 KB); in-place on S.
// ---------------------------------------------------------------------------
__global__ __launch_bounds__(256) void mix_softmax(
    float* __restrict__ S,
    const float* __restrict__ Wl, const float* __restrict__ bl,
    const float* __restrict__ Ww, const float* __restrict__ bw,
    const float* __restrict__ lamb)
{
    const int n = blockIdx.x;
    const int b = blockIdx.y;
    const int tid = threadIdx.x;
    const int lane = tid & 63;
    const int wave = tid >> 6;

    __shared__ float Sm[NH][NSEQ];
    __shared__ float wl[NH * NH], ww[NH * NH];
    __shared__ float blv[NH], cc0[NH], cc1[NH];
    __shared__ float rpart[NH][4];
    __shared__ float rmax[NH], rinvl[NH];

    if (tid < NH * NH) { wl[tid] = Wl[tid]; ww[tid] = Ww[tid]; }
    if (tid < NH) {
        blv[tid] = bl[tid];
        const float lam = lamb[tid];
        cc1[tid] = 1.0f + lam;
        cc0[tid] = (1.0f + lam) * bw[tid] - lam * (1.0f / (float)NSEQ);
    }

    const long long rowbase = ((long long)(b * NH) * NSEQ + n) * NSEQ; // S[b,0,n,0]

    // load 12 head-rows, coalesced float4
    for (int idx = tid; idx < NH * 256; idx += 256) {
        const int h = idx >> 8;
        const int m4 = (idx & 255) << 2;
        *(float4*)&Sm[h][m4] =
            *(const float4*)(S + rowbase + (long long)h * NSEQ * NSEQ + m4);
    }
    __syncthreads();

    // pre-mix across heads, in place (each thread owns columns m ≡ tid mod 256)
    for (int m = tid; m < NSEQ; m += 256) {
        float sh[NH];
#pragma unroll
        for (int h = 0; h < NH; ++h) sh[h] = Sm[h][m];
        float sp[NH];
#pragma unroll
        for (int g = 0; g < NH; ++g) {
            float a = blv[g];
#pragma unroll
            for (int h = 0; h < NH; ++h) a = fmaf(sh[h], wl[g * NH + h], a);
            sp[g] = a;
        }
#pragma unroll
        for (int g = 0; g < NH; ++g) Sm[g][m] = sp[g];
    }
    __syncthreads();

    // per-head row max
    {
        float lmax[NH];
#pragma unroll
        for (int g = 0; g < NH; ++g) lmax[g] = -1e30f;
        for (int m = tid; m < NSEQ; m += 256)
#pragma unroll
            for (int g = 0; g < NH; ++g) lmax[g] = fmaxf(lmax[g], Sm[g][m]);
#pragma unroll
        for (int g = 0; g < NH; ++g) {
            float v = lmax[g];
            for (int off = 32; off > 0; off >>= 1)
                v = fmaxf(v, __shfl_xor(v, off, 64));
            if (lane == 0) rpart[g][wave] = v;
        }
    }
    __syncthreads();
    if (tid < NH)
        rmax[tid] = fmaxf(fmaxf(rpart[tid][0], rpart[tid][1]),
                          fmaxf(rpart[tid][2], rpart[tid][3]));
    __syncthreads();

    // exp + partial sums
    {
        float psum[NH];
#pragma unroll
        for (int g = 0; g < NH; ++g) psum[g] = 0.f;
        for (int m = tid; m < NSEQ; m += 256) {
#pragma unroll
            for (int g = 0; g < NH; ++g) {
                const float e = __expf(Sm[g][m] - rmax[g]);
                Sm[g][m] = e;
                psum[g] += e;
            }
        }
#pragma unroll
        for (int g = 0; g < NH; ++g) {
            float v = psum[g];
            for (int off = 32; off > 0; off >>= 1)
                v += __shfl_xor(v, off, 64);
            if (lane == 0) rpart[g][wave] = v;
        }
    }
    __syncthreads();
    if (tid < NH)
        rinvl[tid] = 1.0f / (rpart[tid][0] + rpart[tid][1] +
                             rpart[tid][2] + rpart[tid][3]);
    __syncthreads();

    // post-mix + attnscale, write back to global
    for (int m = tid; m < NSEQ; m += 256) {
        float p[NH];
#pragma unroll
        for (int h = 0; h < NH; ++h) p[h] = Sm[h][m] * rinvl[h];
#pragma unroll
        for (int g = 0; g < NH; ++g) {
            float a = 0.f;
#pragma unroll
            for (int h = 0; h < NH; ++h) a = fmaf(p[h], ww[g * NH + h], a);
            S[rowbase + (long long)g * NSEQ * NSEQ + m] = cc1[g] * a + cc0[g];
        }
    }
}

extern "C" void kernel_launch(void* const* d_in, const int* in_sizes, int n_in,
                              void* d_out, int out_size, void* d_ws, size_t ws_size,
                              hipStream_t stream) {
    const float* x     = (const float*)d_in[0];
    const float* Wqkv  = (const float*)d_in[1];
    const float* Wproj = (const float*)d_in[2];
    const float* bproj = (const float*)d_in[3];
    const float* Wl    = (const float*)d_in[4];
    const float* bl    = (const float*)d_in[5];
    const float* Ww    = (const float*)d_in[6];
    const float* bw    = (const float*)d_in[7];
    const float* lamb  = (const float*)d_in[8];
    float* out = (float*)d_out;

    float* qkv = (float*)d_ws;                         // [4096][2304]
    float* S   = qkv + (size_t)4096 * 2304;            // [4][12][1024][1024]
    float* ao  = S + (size_t)48 * 1024 * 1024;         // [4096][768]

    // 1. qkv = x @ Wqkv^T          [4096,768] x [2304,768]^T
    gemm_nt<<<dim3(36, 64, 1), 256, 0, stream>>>(
        x, Wqkv, qkv, 768, 768, 2304, 768, 1,
        0, 0, 0, 0, 0, 0, nullptr, 1.0f);

    // 2. S = SCALE * q k^T  per (b,h); q,k live inside qkv with ld=2304
    gemm_nt<<<dim3(16, 16, 48), 256, 0, stream>>>(
        qkv, qkv + 768, S, 2304, 2304, 1024, 64, 12,
        2304LL * 1024, 64, 2304LL * 1024, 64,
        12LL * 1024 * 1024, 1024LL * 1024, nullptr, 0.125f);

    // 3. talking-heads pre -> softmax -> post -> attnscale (in place on S)
    mix_softmax<<<dim3(1024, 4, 1), 256, 0, stream>>>(S, Wl, bl, Ww, bw, lamb);

    // 4. ao[b,n,h*64+d] = sum_m A'[b,h,n,m] v[b,h,m,d]
    gemm_nn<<<dim3(1, 16, 48), 256, 0, stream>>>(
        S, qkv + 1536, ao, 1024, 2304, 768, 1024, 12,
        12LL * 1024 * 1024, 1024LL * 1024, 2304LL * 1024, 64,
        768LL * 1024, 64, nullptr, 1.0f);

    // 5. out = ao @ Wproj^T + bproj
    gemm_nt<<<dim3(12, 64, 1), 256, 0, stream>>>(
        ao, Wproj, out, 768, 768, 768, 768, 1,
        0, 0, 0, 0, 0, 0, bproj, 1.0f);
}

// Round 2
// 239.542 us; speedup vs baseline: 2.5936x; 2.5936x over previous
//
#include <hip/hip_runtime.h>
#include <hip/hip_bf16.h>

// B=4, N=1024, DIM=768, H=12, Dh=64.
// ws layout (bf16 = short):
//   qkvb : [4096][2304]              18.9 MB
//   S    : [4][12][1024][1024]      100.7 MB   (scores -> mixed P', in place)
//   vT   : [4][12][64][1024]          6.3 MB
//   ao   : [4096][768]                6.3 MB

#define NSEQ 1024
#define NH 12

typedef __attribute__((ext_vector_type(8))) short bf16x8;
typedef __attribute__((ext_vector_type(4))) float f32x4;

static __device__ __forceinline__ short f2b(float f) {
    union { __hip_bfloat16 h; short s; } u;
    u.h = __float2bfloat16(f);
    return u.s;
}
static __device__ __forceinline__ float b2f(short s) {
    union { unsigned u; float f; } v;
    v.u = ((unsigned)(unsigned short)s) << 16;
    return v.f;
}

// ---------------------------------------------------------------------------
// bf16 MFMA NT GEMM: C[i][j] = alpha*sum_k A[i][k]*B[j][k] (+bias[j]).
// A: [M][K] row-major (fp32 or bf16; fp32 is cast during LDS staging).
// B: [N][K] row-major (fp32 or bf16).
// C: fp32 or bf16, row-major, ldc.
// Tile BMxBN, 256 threads = 4 waves in 2x2; per wave (BM/2)x(BN/2) via
// 16x16x32 MFMA fragments. BK=32. M%BM==0, N%BN==0, K%32==0 required.
// Batch: z1=z/zdiv, z2=z%zdiv, elem offsets z1*s?1+z2*s?2.
// ---------------------------------------------------------------------------
template<int BM, int BN, bool AF32, bool BF32, bool OUTF32, bool BIAS>
__global__ __launch_bounds__(256) void gemm_mfma(
    const void* __restrict__ Av, const void* __restrict__ Bv, void* __restrict__ Cv,
    int lda, int ldb, int ldc, int K, int zdiv,
    long long sA1, long long sA2, long long sB1, long long sB2,
    long long sC1, long long sC2,
    const float* __restrict__ bias, float alpha)
{
    constexpr int BKP = 40;           // 32 + 8 pad: 80B row stride, 20-bank step
    constexpr int AC = BM / 64;       // A chunks (8 elems) per thread
    constexpr int BC = BN / 64;
    constexpr int FM = BM / 32;       // fragments per wave (M)
    constexpr int FN = BN / 32;

    __shared__ short As[BM * BKP];
    __shared__ short Bs[BN * BKP];

    const int z = blockIdx.z, z1 = z / zdiv, z2 = z % zdiv;
    const long long offA = (long long)z1 * sA1 + (long long)z2 * sA2;
    const long long offB = (long long)z1 * sB1 + (long long)z2 * sB2;
    const long long offC = (long long)z1 * sC1 + (long long)z2 * sC2;

    const int tid = threadIdx.x;
    const int lane = tid & 63, wid = tid >> 6;
    const int wr = wid >> 1, wc = wid & 1;
    const int m0 = blockIdx.y * BM, n0 = blockIdx.x * BN;

    const int arow = wr * (BM / 2) + (lane & 15);
    const int brow = wc * (BN / 2) + (lane & 15);
    const int kb = (lane >> 4) * 8;

    f32x4 acc[FM][FN] = {};

    for (int k0 = 0; k0 < K; k0 += 32) {
        // ---- issue global loads to registers (no LDS dependency) ----
        float4 a0[AC], a1[AC]; bf16x8 ah[AC];
        float4 b0[BC], b1[BC]; bf16x8 bh[BC];
#pragma unroll
        for (int i = 0; i < AC; ++i) {
            const int c = tid + 256 * i;
            const long long e = offA + (long long)(m0 + (c >> 2)) * lda + k0 + (c & 3) * 8;
            if constexpr (AF32) {
                const float* p = (const float*)Av + e;
                a0[i] = *(const float4*)p; a1[i] = *(const float4*)(p + 4);
            } else {
                ah[i] = *(const bf16x8*)((const short*)Av + e);
            }
        }
#pragma unroll
        for (int i = 0; i < BC; ++i) {
            const int c = tid + 256 * i;
            const long long e = offB + (long long)(n0 + (c >> 2)) * ldb + k0 + (c & 3) * 8;
            if constexpr (BF32) {
                const float* p = (const float*)Bv + e;
                b0[i] = *(const float4*)p; b1[i] = *(const float4*)(p + 4);
            } else {
                bh[i] = *(const bf16x8*)((const short*)Bv + e);
            }
        }
        __syncthreads();   // previous iteration's LDS reads done
        // ---- stage to LDS (cast fp32->bf16 here if needed) ----
#pragma unroll
        for (int i = 0; i < AC; ++i) {
            const int c = tid + 256 * i;
            short* dst = &As[(c >> 2) * BKP + (c & 3) * 8];
            if constexpr (AF32) {
                bf16x8 v;
                v[0] = f2b(a0[i].x); v[1] = f2b(a0[i].y); v[2] = f2b(a0[i].z); v[3] = f2b(a0[i].w);
                v[4] = f2b(a1[i].x); v[5] = f2b(a1[i].y); v[6] = f2b(a1[i].z); v[7] = f2b(a1[i].w);
                *(bf16x8*)dst = v;
            } else {
                *(bf16x8*)dst = ah[i];
            }
        }
#pragma unroll
        for (int i = 0; i < BC; ++i) {
            const int c = tid + 256 * i;
            short* dst = &Bs[(c >> 2) * BKP + (c & 3) * 8];
            if constexpr (BF32) {
                bf16x8 v;
                v[0] = f2b(b0[i].x); v[1] = f2b(b0[i].y); v[2] = f2b(b0[i].z); v[3] = f2b(b0[i].w);
                v[4] = f2b(b1[i].x); v[5] = f2b(b1[i].y); v[6] = f2b(b1[i].z); v[7] = f2b(b1[i].w);
                *(bf16x8*)dst = v;
            } else {
                *(bf16x8*)dst = bh[i];
            }
        }
        __syncthreads();
        // ---- fragments + MFMA ----
        bf16x8 af[FM], bfr[FN];
#pragma unroll
        for (int i = 0; i < FM; ++i)
            af[i] = *(const bf16x8*)&As[(arow + i * 16) * BKP + kb];
#pragma unroll
        for (int j = 0; j < FN; ++j)
            bfr[j] = *(const bf16x8*)&Bs[(brow + j * 16) * BKP + kb];
#pragma unroll
        for (int i = 0; i < FM; ++i)
#pragma unroll
            for (int j = 0; j < FN; ++j)
                acc[i][j] = __builtin_amdgcn_mfma_f32_16x16x32_bf16(
                    af[i], bfr[j], acc[i][j], 0, 0, 0);
    }

    // ---- epilogue: C/D layout col=lane&15, row=(lane>>4)*4+r (m89) ----
    const int crow0 = m0 + wr * (BM / 2) + (lane >> 4) * 4;
    const int ccol0 = n0 + wc * (BN / 2) + (lane & 15);
#pragma unroll
    for (int j = 0; j < FN; ++j) {
        const int col = ccol0 + j * 16;
        float badd = 0.f;
        if constexpr (BIAS) badd = bias[col];
#pragma unroll
        for (int i = 0; i < FM; ++i) {
#pragma unroll
            for (int r = 0; r < 4; ++r) {
                const int row = crow0 + i * 16 + r;
                const long long off = offC + (long long)row * ldc + col;
                const float vv = acc[i][j][r] * alpha + badd;
                if constexpr (OUTF32) ((float*)Cv)[off] = vv;
                else                  ((short*)Cv)[off] = f2b(vv);
            }
        }
    }
}

// ---------------------------------------------------------------------------
// v transpose: qkvb bf16 [B*N][2304] (v at col 1536+h*64) -> vT [48][64][1024]
// ---------------------------------------------------------------------------
__global__ __launch_bounds__(256) void vtrans(
    const short* __restrict__ qkvb, short* __restrict__ vT)
{
    __shared__ short t[64][72];
    const int bh = blockIdx.y;
    const int m0 = blockIdx.x * 64;
    const long long src0 = ((long long)(bh / 12) * 1024 + m0) * 2304 + 1536 + (bh % 12) * 64;
#pragma unroll
    for (int i = 0; i < 2; ++i) {
        const int c = threadIdx.x + 256 * i;      // 0..511
        const int m = c >> 3, dc = (c & 7) * 8;
        bf16x8 v = *(const bf16x8*)(qkvb + src0 + (long long)m * 2304 + dc);
#pragma unroll
        for (int j = 0; j < 8; ++j) t[dc + j][m] = v[j];
    }
    __syncthreads();
#pragma unroll
    for (int i = 0; i < 2; ++i) {
        const int c = threadIdx.x + 256 * i;
        const int d = c >> 3, mc = (c & 7) * 8;
        bf16x8 v;
#pragma unroll
        for (int j = 0; j < 8; ++j) v[j] = t[d][mc + j];
        *(bf16x8*)(vT + ((long long)bh * 64 + d) * 1024 + m0 + mc) = v;
    }
}

// ---------------------------------------------------------------------------
// pre-mix (W_l,b_l) -> softmax -> post-mix (W_w,b_w) -> attnscale, in place.
// One block per (b,n); all 12 heads in fp32 LDS; bf16 global I/O.
// ---------------------------------------------------------------------------
__global__ __launch_bounds__(256) void mix_softmax(
    short* __restrict__ S,
    const float* __restrict__ Wl, const float* __restrict__ bl,
    const float* __restrict__ Ww, const float* __restrict__ bw,
    const float* __restrict__ lamb)
{
    const int n = blockIdx.x;
    const int b = blockIdx.y;
    const int tid = threadIdx.x;
    const int lane = tid & 63;
    const int wave = tid >> 6;

    __shared__ float Sm[NH][NSEQ];
    __shared__ float wl[NH * NH], ww[NH * NH];
    __shared__ float blv[NH], cc0[NH], cc1[NH];
    __shared__ float rpart[NH][4];
    __shared__ float rmax[NH], rinvl[NH];

    if (tid < NH * NH) { wl[tid] = Wl[tid]; ww[tid] = Ww[tid]; }
    if (tid < NH) {
        blv[tid] = bl[tid];
        const float lam = lamb[tid];
        cc1[tid] = 1.0f + lam;
        cc0[tid] = (1.0f + lam) * bw[tid] - lam * (1.0f / (float)NSEQ);
    }

    const long long rowbase = ((long long)(b * NH) * NSEQ + n) * NSEQ; // S[b,0,n,0]

    // load 12 head-rows (bf16x8) -> fp32 LDS
#pragma unroll
    for (int i = 0; i < 6; ++i) {
        const int c = tid + 256 * i;          // 0..1535
        const int h = c >> 7;
        const int m8 = (c & 127) << 3;
        bf16x8 v = *(const bf16x8*)(S + rowbase + (long long)h * NSEQ * NSEQ + m8);
#pragma unroll
        for (int j = 0; j < 8; ++j) Sm[h][m8 + j] = b2f(v[j]);
    }
    __syncthreads();

    // pre-mix across heads, in place
    for (int m = tid; m < NSEQ; m += 256) {
        float sh[NH];
#pragma unroll
        for (int h = 0; h < NH; ++h) sh[h] = Sm[h][m];
        float sp[NH];
#pragma unroll
        for (int g = 0; g < NH; ++g) {
            float a = blv[g];
#pragma unroll
            for (int h = 0; h < NH; ++h) a = fmaf(sh[h], wl[g * NH + h], a);
            sp[g] = a;
        }
#pragma unroll
        for (int g = 0; g < NH; ++g) Sm[g][m] = sp[g];
    }
    __syncthreads();

    // per-head row max
    {
        float lmax[NH];
#pragma unroll
        for (int g = 0; g < NH; ++g) lmax[g] = -1e30f;
        for (int m = tid; m < NSEQ; m += 256)
#pragma unroll
            for (int g = 0; g < NH; ++g) lmax[g] = fmaxf(lmax[g], Sm[g][m]);
#pragma unroll
        for (int g = 0; g < NH; ++g) {
            float v = lmax[g];
            for (int off = 32; off > 0; off >>= 1)
                v = fmaxf(v, __shfl_xor(v, off, 64));
            if (lane == 0) rpart[g][wave] = v;
        }
    }
    __syncthreads();
    if (tid < NH)
        rmax[tid] = fmaxf(fmaxf(rpart[tid][0], rpart[tid][1]),
                          fmaxf(rpart[tid][2], rpart[tid][3]));
    __syncthreads();

    // exp + partial sums
    {
        float psum[NH];
#pragma unroll
        for (int g = 0; g < NH; ++g) psum[g] = 0.f;
        for (int m = tid; m < NSEQ; m += 256) {
#pragma unroll
            for (int g = 0; g < NH; ++g) {
                const float e = __expf(Sm[g][m] - rmax[g]);
                Sm[g][m] = e;
                psum[g] += e;
            }
        }
#pragma unroll
        for (int g = 0; g < NH; ++g) {
            float v = psum[g];
            for (int off = 32; off > 0; off >>= 1)
                v += __shfl_xor(v, off, 64);
            if (lane == 0) rpart[g][wave] = v;
        }
    }
    __syncthreads();
    if (tid < NH)
        rinvl[tid] = 1.0f / (rpart[tid][0] + rpart[tid][1] +
                             rpart[tid][2] + rpart[tid][3]);
    __syncthreads();

    // post-mix + attnscale, write back bf16
    for (int m = tid; m < NSEQ; m += 256) {
        float p[NH];
#pragma unroll
        for (int h = 0; h < NH; ++h) p[h] = Sm[h][m] * rinvl[h];
#pragma unroll
        for (int g = 0; g < NH; ++g) {
            float a = 0.f;
#pragma unroll
            for (int h = 0; h < NH; ++h) a = fmaf(p[h], ww[g * NH + h], a);
            S[rowbase + (long long)g * NSEQ * NSEQ + m] = f2b(cc1[g] * a + cc0[g]);
        }
    }
}

extern "C" void kernel_launch(void* const* d_in, const int* in_sizes, int n_in,
                              void* d_out, int out_size, void* d_ws, size_t ws_size,
                              hipStream_t stream) {
    const float* x     = (const float*)d_in[0];
    const float* Wqkv  = (const float*)d_in[1];
    const float* Wproj = (const float*)d_in[2];
    const float* bproj = (const float*)d_in[3];
    const float* Wl    = (const float*)d_in[4];
    const float* bl    = (const float*)d_in[5];
    const float* Ww    = (const float*)d_in[6];
    const float* bw    = (const float*)d_in[7];
    const float* lamb  = (const float*)d_in[8];
    float* out = (float*)d_out;

    short* qkvb = (short*)d_ws;                        // [4096][2304]
    short* S    = qkvb + (size_t)4096 * 2304;          // [48][1024][1024]
    short* vT   = S + (size_t)48 * 1024 * 1024;        // [48][64][1024]
    short* ao   = vT + (size_t)48 * 64 * 1024;         // [4096][768]

    // 1. qkvb = bf16(x @ Wqkv^T)       fp32 in, cast in staging
    gemm_mfma<128, 128, true, true, false, false>
        <<<dim3(18, 32, 1), 256, 0, stream>>>(
        x, Wqkv, qkvb, 768, 768, 2304, 768, 1,
        0, 0, 0, 0, 0, 0, nullptr, 1.0f);

    // 2. vT = transpose of v-slice of qkvb
    vtrans<<<dim3(16, 48, 1), 256, 0, stream>>>(qkvb, vT);

    // 3. S = bf16(SCALE * q k^T) per (b,h)
    gemm_mfma<128, 128, false, false, false, false>
        <<<dim3(8, 8, 48), 256, 0, stream>>>(
        qkvb, qkvb + 768, S, 2304, 2304, 1024, 64, 12,
        2304LL * 1024, 64, 2304LL * 1024, 64,
        12LL * 1024 * 1024, 1024LL * 1024, nullptr, 0.125f);

    // 4. talking-heads pre -> softmax -> post -> attnscale (in place on S)
    mix_softmax<<<dim3(1024, 4, 1), 256, 0, stream>>>(S, Wl, bl, Ww, bw, lamb);

    // 5. ao[b,n,h*64+d] = sum_m P'[b,h,n,m] vT[b,h,d,m]
    gemm_mfma<128, 64, false, false, false, false>
        <<<dim3(1, 8, 48), 256, 0, stream>>>(
        S, vT, ao, 1024, 1024, 768, 1024, 12,
        12LL * 1024 * 1024, 1024LL * 1024,
        12LL * 64 * 1024, 64LL * 1024,
        1024LL * 768, 64, nullptr, 1.0f);

    // 6. out = ao @ Wproj^T + bproj    (fp32 out)
    gemm_mfma<128, 128, false, true, true, true>
        <<<dim3(6, 32, 1), 256, 0, stream>>>(
        ao, Wproj, out, 768, 768, 768, 768, 1,
        0, 0, 0, 0, 0, 0, bproj, 1.0f);
}